// Round 4
// baseline (145.365 us; speedup 1.0000x reference)
//
#include <hip/hip_runtime.h>
#include <hip/hip_bf16.h>
#include <math.h>

#define NN 4096
#define FIN 512
#define HH 8
#define DD 64

typedef unsigned long long u64;
typedef unsigned int u32;
typedef float f32x4 __attribute__((ext_vector_type(4)));
typedef short short8 __attribute__((ext_vector_type(8)));

__device__ inline ushort bf16rne(float f) {
    u32 u = __float_as_uint(f);
    u += 0x7FFFu + ((u >> 16) & 1u);
    return (ushort)(u >> 16);
}
__device__ inline float bf16tof(ushort h) {
    return __uint_as_float(((u32)h) << 16);
}

// ---------- Kernel 1: bit-pack adjacency: bm[i][jw] (u64, bit j%64) ----------
__global__ __launch_bounds__(256) void k_bitpack(const int* __restrict__ adj,
                                                 u64* __restrict__ bm) {
    int tid = blockIdx.x * 256 + threadIdx.x;
    int lane = threadIdx.x & 63;
    int v = adj[tid];
    u64 m = __ballot(v > 0);
    if (lane == 0) bm[tid >> 6] = m;
}

// ---------- Kernel 1b: split x -> bf16 hi/lo ----------
__global__ __launch_bounds__(256) void k_prepx(const float* __restrict__ x,
                                               ushort* __restrict__ xh,
                                               ushort* __restrict__ xl) {
    int tid = blockIdx.x * 256 + threadIdx.x;      // NN*FIN/4 threads
    float4 v = *(const float4*)(x + (size_t)tid * 4);
    float fa[4] = {v.x, v.y, v.z, v.w};
    ushort4 hh, ll;
    ushort* hp = (ushort*)&hh; ushort* lp = (ushort*)&ll;
    #pragma unroll
    for (int k = 0; k < 4; ++k) {
        ushort hv = bf16rne(fa[k]);
        hp[k] = hv;
        lp[k] = bf16rne(fa[k] - bf16tof(hv));
    }
    *(ushort4*)(xh + (size_t)tid * 4) = hh;
    *(ushort4*)(xl + (size_t)tid * 4) = ll;
}

// ---------- Kernel 1c: W[h][f][d] -> WT[h][split][d][f] bf16 hi/lo ----------
__global__ __launch_bounds__(256) void k_prepw(const float* __restrict__ W,
                                               ushort* __restrict__ WT) {
    int tid = blockIdx.x * 256 + threadIdx.x;      // HH*DD*(FIN/4) threads
    int f0 = (tid & 127) * 4;
    int d  = (tid >> 7) & 63;
    int h  = tid >> 13;
    ushort4 hh, ll;
    ushort* hp = (ushort*)&hh; ushort* lp = (ushort*)&ll;
    #pragma unroll
    for (int k = 0; k < 4; ++k) {
        float w = W[((size_t)h * FIN + f0 + k) * DD + d];
        ushort hv = bf16rne(w);
        hp[k] = hv;
        lp[k] = bf16rne(w - bf16tof(hv));
    }
    *(ushort4*)(WT + ((size_t)((h * 2 + 0) * DD) + d) * FIN + f0) = hh;
    *(ushort4*)(WT + ((size_t)((h * 2 + 1) * DD) + d) * FIN + f0) = ll;
}

// ---------- Kernel 2: MFMA projection: WhT = W^T @ x^T (3-term bf16 split) ----------
// grid (NN/64, HH), 256 thr = 4 waves; wave w owns 16 i-cols; M=64 d rows.
// Outputs: WhbT tile format [h][jt][d][64 j] (8KB tiles, linear), s, t.
__global__ __launch_bounds__(256) void k_proj(const ushort* __restrict__ xh,
                                              const ushort* __restrict__ xl,
                                              const ushort* __restrict__ WT,
                                              const float* __restrict__ a_src,
                                              const float* __restrict__ a_dst,
                                              ushort* __restrict__ WhbT,
                                              float* __restrict__ s,
                                              float* __restrict__ t) {
    __shared__ ushort Cls[64][72];   // [d][i], pad 72 (144B rows, 16B-mult)
    __shared__ float als[64], adl[64];
    int h = blockIdx.y, jt = blockIdx.x;
    int i0 = jt * 64;
    int tid = threadIdx.x, w = tid >> 6, lane = tid & 63, lm = lane & 15, g = lane >> 4;
    if (tid < 64) als[tid] = a_src[h * DD + tid];
    else if (tid < 128) adl[tid - 64] = a_dst[h * DD + tid - 64];
    int i = i0 + w * 16 + lm;
    const ushort* xhp = xh + (size_t)i * FIN + g * 8;
    const ushort* xlp = xl + (size_t)i * FIN + g * 8;
    const ushort* wh0 = WT + ((size_t)((h * 2 + 0) * DD) + lm) * FIN + g * 8;
    const ushort* wl0 = WT + ((size_t)((h * 2 + 1) * DD) + lm) * FIN + g * 8;
    f32x4 acc[4] = {};
    for (int kb = 0; kb < FIN; kb += 32) {
        short8 bh = *(const short8*)(xhp + kb);
        short8 bl = *(const short8*)(xlp + kb);
        #pragma unroll
        for (int cf = 0; cf < 4; ++cf) {
            short8 ah = *(const short8*)(wh0 + (size_t)cf * 16 * FIN + kb);
            short8 al = *(const short8*)(wl0 + (size_t)cf * 16 * FIN + kb);
            acc[cf] = __builtin_amdgcn_mfma_f32_16x16x32_bf16(ah, bh, acc[cf], 0, 0, 0);
            acc[cf] = __builtin_amdgcn_mfma_f32_16x16x32_bf16(al, bh, acc[cf], 0, 0, 0);
            acc[cf] = __builtin_amdgcn_mfma_f32_16x16x32_bf16(ah, bl, acc[cf], 0, 0, 0);
        }
    }
    __syncthreads();   // als/adl visible
    // s,t: lane holds d = cf*16 + g*4 + reg for its col i; reduce over g.
    float sp = 0.f, tp = 0.f;
    #pragma unroll
    for (int cf = 0; cf < 4; ++cf)
        #pragma unroll
        for (int reg = 0; reg < 4; ++reg) {
            int d = cf * 16 + g * 4 + reg;
            sp += acc[cf][reg] * als[d];
            tp += acc[cf][reg] * adl[d];
            Cls[d][w * 16 + lm] = bf16rne(acc[cf][reg]);
        }
    sp += __shfl_xor(sp, 16); sp += __shfl_xor(sp, 32);
    tp += __shfl_xor(tp, 16); tp += __shfl_xor(tp, 32);
    if (g == 0) { s[h * NN + i] = sp; t[h * NN + i] = tp; }
    __syncthreads();
    // store tile: 512 chunks of 16B, linear [d][j]
    ushort* tbase = WhbT + ((size_t)(h * 64 + jt)) * 4096;
    #pragma unroll
    for (int c = tid; c < 512; c += 256) {
        int d = c >> 3, jg = c & 7;
        uint4 v = *(const uint4*)&Cls[d][jg * 8];
        *(uint4*)(tbase + (size_t)c * 8) = v;
    }
}

// ---------- Kernel 3: partial masked-softmax aggregation via MFMA (j-split) ----------
// grid (NN/64, HH, js); block 256 = 4 waves, wave owns 16 rows.
__global__ __launch_bounds__(256) void k_aggp(const ushort* __restrict__ WhbT,
                                              const float* __restrict__ s,
                                              const float* __restrict__ t,
                                              const u64* __restrict__ bm,
                                              float* __restrict__ pacc,
                                              float* __restrict__ pl,
                                              int ntiles) {
    __shared__ ushort Vt[4096];     // 8KB, XOR-swizzled [d][j]
    __shared__ float tls[64];
    __shared__ u64 bmls[64];
    int h = blockIdx.y;
    int i0 = blockIdx.x * 64;
    int z = blockIdx.z;
    int tid = threadIdx.x;
    int w = tid >> 6, lane = tid & 63, lm = lane & 15, g = lane >> 4;
    const float LOG2E = 1.4426950408889634f;
    float s_i = s[h * NN + i0 + w * 16 + lm] * LOG2E;
    f32x4 acc[4] = {};
    f32x4 accl = {};
    short8 ones;
    #pragma unroll
    for (int e = 0; e < 8; ++e) ones[e] = (short)0x3F80;
    int jt0 = z * ntiles;
    // per-thread staging coords (2 chunks of 16B)
    int c0 = tid * 2;
    u32 wsw = (u32)(((c0 >> 3) & 7) << 4);
    u32 wo0 = ((u32)c0 * 16) ^ wsw;
    u32 wo1 = ((u32)(c0 + 1) * 16) ^ wsw;
    for (int jj = 0; jj < ntiles; ++jj) {
        int jt = jt0 + jj, j0 = jt * 64;
        // issue global loads early (overlap with prev tile's compute)
        const uint4* gsrc = (const uint4*)(WhbT + ((size_t)(h * 64 + jt)) * 4096);
        uint4 va = gsrc[c0];
        uint4 vb = gsrc[c0 + 1];
        u64 bmv = 0; float tv = 0.f;
        if (tid < 64) bmv = bm[(size_t)(i0 + tid) * 64 + jt];
        if (tid >= 192) tv = t[h * NN + j0 + (tid - 192)] * LOG2E;
        __syncthreads();    // prev tile's LDS reads done
        *(uint4*)((char*)Vt + wo0) = va;
        *(uint4*)((char*)Vt + wo1) = vb;
        if (tid < 64) bmls[tid] = bmv;
        if (tid >= 192) tls[tid - 192] = tv;
        __syncthreads();
        u64 bits = bmls[w * 16 + lm];
        #pragma unroll
        for (int ks = 0; ks < 2; ++ks) {
            int kb = ks * 32 + g * 8;
            u32 msk = (u32)(bits >> kb) & 0xffu;
            short8 a;
            #pragma unroll
            for (int e = 0; e < 8; ++e) {
                float z2 = s_i + tls[kb + e];
                z2 = fmaxf(z2, 0.2f * z2);         // LeakyReLU (log2-domain)
                float ex = exp2f(z2);
                a[e] = (short)bf16rne(((msk >> e) & 1u) ? ex : 0.f);
            }
            accl = __builtin_amdgcn_mfma_f32_16x16x32_bf16(a, ones, accl, 0, 0, 0);
            #pragma unroll
            for (int cf = 0; cf < 4; ++cf) {
                int d = cf * 16 + lm;
                u32 off = ((u32)(d * 128 + ks * 64 + g * 16)) ^ ((u32)((d & 7) << 4));
                short8 b = *(const short8*)((const char*)Vt + off);
                acc[cf] = __builtin_amdgcn_mfma_f32_16x16x32_bf16(a, b, acc[cf], 0, 0, 0);
            }
        }
    }
    // store partials: C layout col=lm, row=g*4+reg
    size_t pbase = ((size_t)z * HH + h) * NN;
    #pragma unroll
    for (int reg = 0; reg < 4; ++reg) {
        int i = i0 + w * 16 + g * 4 + reg;
        if (lm == 0) pl[pbase + i] = accl[reg];
        #pragma unroll
        for (int cf = 0; cf < 4; ++cf)
            pacc[(pbase + i) * DD + cf * 16 + lm] = acc[cf][reg];
    }
}

// ---------- Kernel 4: combine partials, normalize, ELU ----------
__global__ __launch_bounds__(256) void k_comb(const float* __restrict__ pacc,
                                              const float* __restrict__ pl,
                                              float* __restrict__ out, int js) {
    int gid = blockIdx.x * 256 + threadIdx.x;   // H*N*16 threads, 4 d's each
    int dgi = gid & 15;
    int hn = gid >> 4;
    int h = hn >> 12, n = hn & (NN - 1);
    f32x4 acc = {};
    float l = 0.f;
    for (int zz = 0; zz < js; ++zz) {
        const f32x4* p = (const f32x4*)(pacc + ((size_t)zz * HH * NN + hn) * DD + dgi * 4);
        acc += *p;
        l += pl[(size_t)zz * HH * NN + hn];
    }
    float inv = 1.f / l;
    float r[4];
    #pragma unroll
    for (int dd = 0; dd < 4; ++dd) {
        float u = acc[dd] * inv;
        r[dd] = u > 0.f ? u : __expf(u) - 1.f;
    }
    *(float4*)&out[(size_t)n * (HH * DD) + h * DD + dgi * 4] =
        make_float4(r[0], r[1], r[2], r[3]);
}

extern "C" void kernel_launch(void* const* d_in, const int* in_sizes, int n_in,
                              void* d_out, int out_size, void* d_ws, size_t ws_size,
                              hipStream_t stream) {
    const float* x     = (const float*)d_in[0];
    const int*   adj   = (const int*)d_in[1];
    const float* W     = (const float*)d_in[2];
    const float* a_src = (const float*)d_in[3];
    const float* a_dst = (const float*)d_in[4];
    float* out = (float*)d_out;

    char* ws = (char*)d_ws;
    const size_t MB = 1024 * 1024;
    ushort* WhbT = (ushort*)ws;                         // 4 MB, tile format
    u64*    bm   = (u64*)(ws + 4 * MB);                 // 2 MB
    float*  s    = (float*)(ws + 6 * MB);               // 128 KB
    float*  t    = (float*)(ws + 6 * MB + 128 * 1024);  // 128 KB
    // early region (dead after k_proj) — pacc aliases it
    ushort* xh = (ushort*)(ws + 6 * MB + 256 * 1024);               // 4 MB
    ushort* xl = (ushort*)(ws + 10 * MB + 256 * 1024);              // 4 MB
    ushort* WT = (ushort*)(ws + 14 * MB + 256 * 1024);              // 1 MB
    size_t pacc_off = 6 * MB + 256 * 1024;

    size_t per = (size_t)HH * NN * DD * 4;              // pacc bytes per split
    size_t perl = (size_t)HH * NN * 4;                  // pl bytes per split
    int js = 4;
    while (js > 1 && pacc_off + (size_t)js * (per + perl) > ws_size) js >>= 1;
    float* pacc = (float*)(ws + pacc_off);
    float* pl   = (float*)(ws + pacc_off + (size_t)js * per);
    int ntiles = (NN / 64) / js;

    k_bitpack<<<dim3(NN * NN / 256), dim3(256), 0, stream>>>(adj, bm);
    k_prepx<<<dim3(NN * FIN / 4 / 256), dim3(256), 0, stream>>>(x, xh, xl);
    k_prepw<<<dim3(HH * DD * (FIN / 4) / 256), dim3(256), 0, stream>>>(W, WT);
    k_proj<<<dim3(NN / 64, HH), dim3(256), 0, stream>>>(xh, xl, WT, a_src, a_dst, WhbT, s, t);
    k_aggp<<<dim3(NN / 64, HH, js), dim3(256), 0, stream>>>(WhbT, s, t, bm, pacc, pl, ntiles);
    k_comb<<<dim3(HH * NN * 16 / 256), dim3(256), 0, stream>>>(pacc, pl, out, js);
}

// Round 5
// 108.504 us; speedup vs baseline: 1.3397x; 1.3397x over previous
//
#include <hip/hip_runtime.h>
#include <hip/hip_bf16.h>
#include <math.h>

#define NN 4096
#define FIN 512
#define HH 8
#define DD 64

typedef unsigned long long u64;
typedef unsigned int u32;
typedef float f32x4 __attribute__((ext_vector_type(4)));
typedef short short8 __attribute__((ext_vector_type(8)));

#define GLOAD_LDS16(g, l)                                                              \
  __builtin_amdgcn_global_load_lds((const __attribute__((address_space(1))) u32*)(g),  \
                                   (__attribute__((address_space(3))) u32*)(l), 16, 0, 0)

#if __has_builtin(__builtin_amdgcn_exp2f)
#define EXP2F(x) __builtin_amdgcn_exp2f(x)
#else
#define EXP2F(x) exp2f(x)
#endif

__device__ inline ushort bf16rne(float f) {
    u32 u = __float_as_uint(f);
    u += 0x7FFFu + ((u >> 16) & 1u);
    return (ushort)(u >> 16);
}
__device__ inline float bf16tof(ushort h) {
    return __uint_as_float(((u32)h) << 16);
}

// ---------- Kernel 1: bit-pack adjacency: bm[i][jw] (u64, bit j%64) ----------
__global__ __launch_bounds__(256) void k_bitpack(const int* __restrict__ adj,
                                                 u64* __restrict__ bm) {
    int tid = blockIdx.x * 256 + threadIdx.x;
    int lane = threadIdx.x & 63;
    int v = adj[tid];
    u64 m = __ballot(v > 0);
    if (lane == 0) bm[tid >> 6] = m;
}

// ---------- Kernel 1b: split x -> bf16 hi/lo (row-major [i][f]) ----------
__global__ __launch_bounds__(256) void k_prepx(const float* __restrict__ x,
                                               ushort* __restrict__ xh,
                                               ushort* __restrict__ xl) {
    int tid = blockIdx.x * 256 + threadIdx.x;      // NN*FIN/4 threads
    float4 v = *(const float4*)(x + (size_t)tid * 4);
    float fa[4] = {v.x, v.y, v.z, v.w};
    ushort4 hh, ll;
    ushort* hp = (ushort*)&hh; ushort* lp = (ushort*)&ll;
    #pragma unroll
    for (int k = 0; k < 4; ++k) {
        ushort hv = bf16rne(fa[k]);
        hp[k] = hv;
        lp[k] = bf16rne(fa[k] - bf16tof(hv));
    }
    *(ushort4*)(xh + (size_t)tid * 4) = hh;
    *(ushort4*)(xl + (size_t)tid * 4) = ll;
}

// ---------- Kernel 1c: W -> WTs tiles [h*2+split][kt][d(64)][k(64)] bf16, linear ----------
__global__ __launch_bounds__(256) void k_prepw(const float* __restrict__ W,
                                               ushort* __restrict__ WTs) {
    int gid = blockIdx.x * 256 + threadIdx.x;      // 32768 threads
    int d = gid & 63, kg = (gid >> 6) & 7, kt = (gid >> 9) & 7, h = gid >> 12;
    ushort hh[8], ll[8];
    #pragma unroll
    for (int e = 0; e < 8; ++e) {
        int f = kt * 64 + kg * 8 + e;
        float wv = W[((size_t)h * FIN + f) * DD + d];
        ushort hv = bf16rne(wv);
        hh[e] = hv;
        ll[e] = bf16rne(wv - bf16tof(hv));
    }
    *(uint4*)(WTs + ((size_t)((h * 2 + 0) * 8 + kt)) * 4096 + d * 64 + kg * 8) = *(uint4*)hh;
    *(uint4*)(WTs + ((size_t)((h * 2 + 1) * 8 + kt)) * 4096 + d * 64 + kg * 8) = *(uint4*)ll;
}

// ---------- Kernel 2: MFMA projection, LDS-staged, 16 waves/block ----------
// grid (NN/64, HH), 1024 thr. wave w: w_c=w&3 (d-subtile), w_i=w>>2 (i-subtile).
// Outputs: WhbT linear tiles [h][it][d(64)][j(64)] bf16; s,t pre-scaled by log2e.
__global__ __launch_bounds__(1024) void k_proj(const ushort* __restrict__ xh,
                                               const ushort* __restrict__ xl,
                                               const ushort* __restrict__ WTs,
                                               const float* __restrict__ a_src,
                                               const float* __restrict__ a_dst,
                                               ushort* __restrict__ WhbT,
                                               float* __restrict__ s,
                                               float* __restrict__ t) {
    __shared__ ushort P[16384];        // 4 bufs (Ah,Al,Bh,Bl) x 8KB, swizzled image
    __shared__ float SP[64][5], TP[64][5];
    int h = blockIdx.y, it = blockIdx.x;
    int i0 = it * 64;
    int tid = threadIdx.x;
    int w = tid >> 6, lane = tid & 63, lm = lane & 15, g = lane >> 4;
    int w_c = w & 3, w_i = w >> 2;
    f32x4 acc = {};
    int da = w_c * 16 + lm, ib = w_i * 16 + lm;
    for (int kt = 0; kt < 8; ++kt) {
        // stage 32KB: each thread 2 chunks of 16B, sigma-permuted source
        #pragma unroll
        for (int sub = 0; sub < 2; ++sub) {
            int buf = sub * 2 + (w >> 3);          // wave-uniform
            int y0 = (w & 7) * 64;                 // wave-uniform chunk base
            int y = y0 + lane;
            int r = y >> 3;
            int cc = (y & 7) ^ (r & 7);            // sigma: inverse-swizzle source
            const ushort* src;
            if (buf == 0)      src = WTs + ((size_t)((h * 2 + 0) * 8 + kt)) * 4096 + r * 64 + cc * 8;
            else if (buf == 1) src = WTs + ((size_t)((h * 2 + 1) * 8 + kt)) * 4096 + r * 64 + cc * 8;
            else if (buf == 2) src = xh + (size_t)(i0 + r) * FIN + kt * 64 + cc * 8;
            else               src = xl + (size_t)(i0 + r) * FIN + kt * 64 + cc * 8;
            GLOAD_LDS16(src, P + buf * 4096 + y0 * 8);
        }
        __syncthreads();
        #pragma unroll
        for (int ks = 0; ks < 2; ++ks) {
            u32 offA = ((u32)(da * 128 + ks * 64 + g * 16)) ^ ((u32)(da & 7) << 4);
            u32 offB = ((u32)(ib * 128 + ks * 64 + g * 16)) ^ ((u32)(ib & 7) << 4);
            short8 ah = *(const short8*)((const char*)P + offA);
            short8 al = *(const short8*)((const char*)P + 8192 + offA);
            short8 bh = *(const short8*)((const char*)P + 16384 + offB);
            short8 bl = *(const short8*)((const char*)P + 24576 + offB);
            acc = __builtin_amdgcn_mfma_f32_16x16x32_bf16(ah, bh, acc, 0, 0, 0);
            acc = __builtin_amdgcn_mfma_f32_16x16x32_bf16(al, bh, acc, 0, 0, 0);
            acc = __builtin_amdgcn_mfma_f32_16x16x32_bf16(ah, bl, acc, 0, 0, 0);
        }
        __syncthreads();
    }
    // epilogue: s,t partials + C tile. C[row=d=w_c*16+g*4+reg][col=i=w_i*16+lm]
    float4 as4 = *(const float4*)(a_src + h * DD + w_c * 16 + g * 4);
    float4 ad4 = *(const float4*)(a_dst + h * DD + w_c * 16 + g * 4);
    float sp = acc[0] * as4.x + acc[1] * as4.y + acc[2] * as4.z + acc[3] * as4.w;
    float tp = acc[0] * ad4.x + acc[1] * ad4.y + acc[2] * ad4.z + acc[3] * ad4.w;
    sp += __shfl_xor(sp, 16); sp += __shfl_xor(sp, 32);
    tp += __shfl_xor(tp, 16); tp += __shfl_xor(tp, 32);
    if (lane < 16) { SP[w_i * 16 + lm][w_c] = sp; TP[w_i * 16 + lm][w_c] = tp; }
    #pragma unroll
    for (int reg = 0; reg < 4; ++reg) {
        int d = w_c * 16 + g * 4 + reg;
        P[d * 64 + w_i * 16 + lm] = bf16rne(acc[reg]);
    }
    __syncthreads();
    const float LOG2E = 1.4426950408889634f;
    if (tid < 64) {
        int i = i0 + tid;
        s[h * NN + i] = (SP[tid][0] + SP[tid][1] + SP[tid][2] + SP[tid][3]) * LOG2E;
        t[h * NN + i] = (TP[tid][0] + TP[tid][1] + TP[tid][2] + TP[tid][3]) * LOG2E;
    }
    ushort* tbase = WhbT + ((size_t)(h * 64 + it)) * 4096;
    if (tid < 512) {
        uint4 v = *(const uint4*)(P + tid * 8);
        *(uint4*)(tbase + tid * 8) = v;
    }
}

// ---------- Kernel 3: partial masked-softmax aggregation via MFMA (j-split) ----------
// grid (NN/64, HH, js); 256 thr = 4 waves. Double-buffered Vt, 1 barrier/tile.
__global__ __launch_bounds__(256) void k_aggp(const ushort* __restrict__ WhbT,
                                              const float* __restrict__ s,
                                              const float* __restrict__ t,
                                              const u64* __restrict__ bm,
                                              float* __restrict__ pacc,
                                              float* __restrict__ pl,
                                              int ntiles) {
    __shared__ ushort Vt[8192];     // 2 bufs x 8KB, swizzled image
    int h = blockIdx.y;
    int i0 = blockIdx.x * 64;
    int z = blockIdx.z;
    int tid = threadIdx.x;
    int w = tid >> 6, lane = tid & 63, lm = lane & 15, g = lane >> 4;
    int irow = i0 + w * 16 + lm;
    float s_i = s[h * NN + irow];           // pre-scaled by log2e
    const float* tbase_t = t + (size_t)h * NN;
    f32x4 acc[4] = {};
    f32x4 accl = {};
    short8 ones;
    #pragma unroll
    for (int e = 0; e < 8; ++e) ones[e] = (short)0x3F80;
    int jt0 = z * ntiles;
    auto stage = [&](int p, int jt) {
        const ushort* tb = WhbT + ((size_t)(h * 64 + jt)) * 4096;
        #pragma unroll
        for (int sub = 0; sub < 2; ++sub) {
            int y0 = sub * 256 + w * 64;           // wave-uniform
            int y = y0 + lane;
            int sy = y ^ ((y >> 3) & 7);           // sigma source chunk
            GLOAD_LDS16(tb + sy * 8, Vt + p * 4096 + y0 * 8);
        }
    };
    stage(0, jt0);
    int p = 0;
    for (int jj = 0; jj < ntiles; ++jj) {
        int jt = jt0 + jj, j0 = jt * 64;
        __syncthreads();                 // buf[p] DMA complete; prev reads done
        if (jj + 1 < ntiles) stage(p ^ 1, jt + 1);
        u64 bits = bm[(size_t)irow * 64 + jt];
        #pragma unroll
        for (int ks = 0; ks < 2; ++ks) {
            int kb = ks * 32 + g * 8;
            float4 t0 = *(const float4*)(tbase_t + j0 + kb);
            float4 t1 = *(const float4*)(tbase_t + j0 + kb + 4);
            float ta[8] = {t0.x, t0.y, t0.z, t0.w, t1.x, t1.y, t1.z, t1.w};
            u32 msk = (u32)(bits >> kb) & 0xffu;
            float wv[8];
            #pragma unroll
            for (int e = 0; e < 8; ++e) {
                float zz = s_i + ta[e];
                zz = fmaxf(zz, 0.2f * zz);          // LeakyReLU (log2-domain)
                float ex = EXP2F(zz);
                wv[e] = ((msk >> e) & 1u) ? ex : 0.f;
            }
            union { u32 u[4]; short8 v; } au;
            #pragma unroll
            for (int q = 0; q < 4; ++q) {
                __hip_bfloat162 b2 = __float22bfloat162_rn(make_float2(wv[2 * q], wv[2 * q + 1]));
                au.u[q] = *(u32*)&b2;
            }
            __builtin_amdgcn_s_setprio(1);
            accl = __builtin_amdgcn_mfma_f32_16x16x32_bf16(au.v, ones, accl, 0, 0, 0);
            #pragma unroll
            for (int cf = 0; cf < 4; ++cf) {
                int d = cf * 16 + lm;
                u32 off = (u32)(p * 8192) +
                          (((u32)(d * 128 + ks * 64 + g * 16)) ^ ((u32)(d & 7) << 4));
                short8 b = *(const short8*)((const char*)Vt + off);
                acc[cf] = __builtin_amdgcn_mfma_f32_16x16x32_bf16(au.v, b, acc[cf], 0, 0, 0);
            }
            __builtin_amdgcn_s_setprio(0);
        }
        p ^= 1;
    }
    // store partials: C layout col=lm, row=g*4+reg
    size_t pbase = ((size_t)z * HH + h) * NN;
    #pragma unroll
    for (int reg = 0; reg < 4; ++reg) {
        int i = i0 + w * 16 + g * 4 + reg;
        if (lm == 0) pl[pbase + i] = accl[reg];
        #pragma unroll
        for (int cf = 0; cf < 4; ++cf)
            pacc[(pbase + i) * DD + cf * 16 + lm] = acc[cf][reg];
    }
}

// ---------- Kernel 4: combine partials, normalize, ELU ----------
__global__ __launch_bounds__(256) void k_comb(const float* __restrict__ pacc,
                                              const float* __restrict__ pl,
                                              float* __restrict__ out, int js) {
    int gid = blockIdx.x * 256 + threadIdx.x;   // H*N*16 threads, 4 d's each
    int dgi = gid & 15;
    int hn = gid >> 4;
    int h = hn >> 12, n = hn & (NN - 1);
    f32x4 acc = {};
    float l = 0.f;
    for (int zz = 0; zz < js; ++zz) {
        const f32x4* pp = (const f32x4*)(pacc + ((size_t)zz * HH * NN + hn) * DD + dgi * 4);
        acc += *pp;
        l += pl[(size_t)zz * HH * NN + hn];
    }
    float inv = 1.f / l;
    float r[4];
    #pragma unroll
    for (int dd = 0; dd < 4; ++dd) {
        float u = acc[dd] * inv;
        r[dd] = u > 0.f ? u : __expf(u) - 1.f;
    }
    *(float4*)&out[(size_t)n * (HH * DD) + h * DD + dgi * 4] =
        make_float4(r[0], r[1], r[2], r[3]);
}

extern "C" void kernel_launch(void* const* d_in, const int* in_sizes, int n_in,
                              void* d_out, int out_size, void* d_ws, size_t ws_size,
                              hipStream_t stream) {
    const float* x     = (const float*)d_in[0];
    const int*   adj   = (const int*)d_in[1];
    const float* W     = (const float*)d_in[2];
    const float* a_src = (const float*)d_in[3];
    const float* a_dst = (const float*)d_in[4];
    float* out = (float*)d_out;

    char* ws = (char*)d_ws;
    const size_t MB = 1024 * 1024;
    ushort* WhbT = (ushort*)ws;                         // 4 MB, linear tiles
    u64*    bm   = (u64*)(ws + 4 * MB);                 // 2 MB
    float*  s    = (float*)(ws + 6 * MB);               // 128 KB
    float*  t    = (float*)(ws + 6 * MB + 128 * 1024);  // 128 KB
    // early region (dead after k_proj) — pacc aliases it
    ushort* xh  = (ushort*)(ws + 6 * MB + 256 * 1024);              // 4 MB
    ushort* xl  = (ushort*)(ws + 10 * MB + 256 * 1024);             // 4 MB
    ushort* WTs = (ushort*)(ws + 14 * MB + 256 * 1024);             // 1 MB
    size_t pacc_off = 6 * MB + 256 * 1024;

    size_t per  = (size_t)HH * NN * DD * 4;             // pacc bytes per split
    size_t perl = (size_t)HH * NN * 4;                  // pl bytes per split
    int js = 4;
    while (js > 1 && pacc_off + (size_t)js * (per + perl) > ws_size) js >>= 1;
    float* pacc = (float*)(ws + pacc_off);
    float* pl   = (float*)(ws + pacc_off + (size_t)js * per);
    int ntiles = (NN / 64) / js;

    k_bitpack<<<dim3(NN * NN / 256), dim3(256), 0, stream>>>(adj, bm);
    k_prepx<<<dim3(NN * FIN / 4 / 256), dim3(256), 0, stream>>>(x, xh, xl);
    k_prepw<<<dim3(HH * 8 * 64 * 8 / 256), dim3(256), 0, stream>>>(W, WTs);
    k_proj<<<dim3(NN / 64, HH), dim3(1024), 0, stream>>>(xh, xl, WTs, a_src, a_dst, WhbT, s, t);
    k_aggp<<<dim3(NN / 64, HH, js), dim3(256), 0, stream>>>(WhbT, s, t, bm, pacc, pl, ntiles);
    k_comb<<<dim3(HH * NN * 16 / 256), dim3(256), 0, stream>>>(pacc, pl, out, js);
}

// Round 6
// 107.210 us; speedup vs baseline: 1.3559x; 1.0121x over previous
//
#include <hip/hip_runtime.h>
#include <hip/hip_bf16.h>
#include <math.h>

#define NN 4096
#define FIN 512
#define HH 8
#define DD 64

typedef unsigned long long u64;
typedef unsigned int u32;
typedef float f32x4 __attribute__((ext_vector_type(4)));
typedef float f32x16 __attribute__((ext_vector_type(16)));
typedef short short8 __attribute__((ext_vector_type(8)));

#define GLOAD_LDS16(g, l)                                                              \
  __builtin_amdgcn_global_load_lds((const __attribute__((address_space(1))) u32*)(g),  \
                                   (__attribute__((address_space(3))) u32*)(l), 16, 0, 0)

#if __has_builtin(__builtin_amdgcn_exp2f)
#define EXP2F(x) __builtin_amdgcn_exp2f(x)
#else
#define EXP2F(x) exp2f(x)
#endif

__device__ inline ushort bf16rne(float f) {
    u32 u = __float_as_uint(f);
    u += 0x7FFFu + ((u >> 16) & 1u);
    return (ushort)(u >> 16);
}
__device__ inline float bf16tof(ushort h) {
    return __uint_as_float(((u32)h) << 16);
}

// ---------- Kernel 1: bit-pack adjacency: bm[i][jw] (u64, bit j%64) ----------
__global__ __launch_bounds__(256) void k_bitpack(const int* __restrict__ adj,
                                                 u64* __restrict__ bm) {
    int tid = blockIdx.x * 256 + threadIdx.x;
    int lane = threadIdx.x & 63;
    int v = adj[tid];
    u64 m = __ballot(v > 0);
    if (lane == 0) bm[tid >> 6] = m;
}

// ---------- Kernel 1b: split x -> bf16 hi/lo (row-major [i][f]) ----------
__global__ __launch_bounds__(256) void k_prepx(const float* __restrict__ x,
                                               ushort* __restrict__ xh,
                                               ushort* __restrict__ xl) {
    int tid = blockIdx.x * 256 + threadIdx.x;      // NN*FIN/4 threads
    float4 v = *(const float4*)(x + (size_t)tid * 4);
    float fa[4] = {v.x, v.y, v.z, v.w};
    ushort4 hh, ll;
    ushort* hp = (ushort*)&hh; ushort* lp = (ushort*)&ll;
    #pragma unroll
    for (int k = 0; k < 4; ++k) {
        ushort hv = bf16rne(fa[k]);
        hp[k] = hv;
        lp[k] = bf16rne(fa[k] - bf16tof(hv));
    }
    *(ushort4*)(xh + (size_t)tid * 4) = hh;
    *(ushort4*)(xl + (size_t)tid * 4) = ll;
}

// ---------- Kernel 1c: W -> WTs tiles [h*2+split][kt][d(64)][k(64)] bf16, linear ----------
__global__ __launch_bounds__(256) void k_prepw(const float* __restrict__ W,
                                               ushort* __restrict__ WTs) {
    int gid = blockIdx.x * 256 + threadIdx.x;      // 32768 threads
    int d = gid & 63, kg = (gid >> 6) & 7, kt = (gid >> 9) & 7, h = gid >> 12;
    ushort hh[8], ll[8];
    #pragma unroll
    for (int e = 0; e < 8; ++e) {
        int f = kt * 64 + kg * 8 + e;
        float wv = W[((size_t)h * FIN + f) * DD + d];
        ushort hv = bf16rne(wv);
        hh[e] = hv;
        ll[e] = bf16rne(wv - bf16tof(hv));
    }
    *(uint4*)(WTs + ((size_t)((h * 2 + 0) * 8 + kt)) * 4096 + d * 64 + kg * 8) = *(uint4*)hh;
    *(uint4*)(WTs + ((size_t)((h * 2 + 1) * 8 + kt)) * 4096 + d * 64 + kg * 8) = *(uint4*)ll;
}

// ---------- Kernel 2: MFMA projection, LDS-staged, 16 waves/block ----------
// grid (NN/64, HH), 1024 thr. wave w: w_c=w&3 (d-subtile), w_i=w>>2 (i-subtile).
// Outputs: WhbT linear tiles [h][it][d(64)][j(64)] bf16; s,t pre-scaled by log2e.
__global__ __launch_bounds__(1024) void k_proj(const ushort* __restrict__ xh,
                                               const ushort* __restrict__ xl,
                                               const ushort* __restrict__ WTs,
                                               const float* __restrict__ a_src,
                                               const float* __restrict__ a_dst,
                                               ushort* __restrict__ WhbT,
                                               float* __restrict__ s,
                                               float* __restrict__ t) {
    __shared__ ushort P[16384];        // 4 bufs (Ah,Al,Bh,Bl) x 8KB, swizzled image
    __shared__ float SP[64][5], TP[64][5];
    int h = blockIdx.y, it = blockIdx.x;
    int i0 = it * 64;
    int tid = threadIdx.x;
    int w = tid >> 6, lane = tid & 63, lm = lane & 15, g = lane >> 4;
    int w_c = w & 3, w_i = w >> 2;
    f32x4 acc = {};
    int da = w_c * 16 + lm, ib = w_i * 16 + lm;
    for (int kt = 0; kt < 8; ++kt) {
        // stage 32KB: each thread 2 chunks of 16B, sigma-permuted source
        #pragma unroll
        for (int sub = 0; sub < 2; ++sub) {
            int buf = sub * 2 + (w >> 3);          // wave-uniform
            int y0 = (w & 7) * 64;                 // wave-uniform chunk base
            int y = y0 + lane;
            int r = y >> 3;
            int cc = (y & 7) ^ (r & 7);            // sigma: inverse-swizzle source
            const ushort* src;
            if (buf == 0)      src = WTs + ((size_t)((h * 2 + 0) * 8 + kt)) * 4096 + r * 64 + cc * 8;
            else if (buf == 1) src = WTs + ((size_t)((h * 2 + 1) * 8 + kt)) * 4096 + r * 64 + cc * 8;
            else if (buf == 2) src = xh + (size_t)(i0 + r) * FIN + kt * 64 + cc * 8;
            else               src = xl + (size_t)(i0 + r) * FIN + kt * 64 + cc * 8;
            GLOAD_LDS16(src, P + buf * 4096 + y0 * 8);
        }
        __syncthreads();
        #pragma unroll
        for (int ks = 0; ks < 2; ++ks) {
            u32 offA = ((u32)(da * 128 + ks * 64 + g * 16)) ^ ((u32)(da & 7) << 4);
            u32 offB = ((u32)(ib * 128 + ks * 64 + g * 16)) ^ ((u32)(ib & 7) << 4);
            short8 ah = *(const short8*)((const char*)P + offA);
            short8 al = *(const short8*)((const char*)P + 8192 + offA);
            short8 bh = *(const short8*)((const char*)P + 16384 + offB);
            short8 bl = *(const short8*)((const char*)P + 24576 + offB);
            acc = __builtin_amdgcn_mfma_f32_16x16x32_bf16(ah, bh, acc, 0, 0, 0);
            acc = __builtin_amdgcn_mfma_f32_16x16x32_bf16(al, bh, acc, 0, 0, 0);
            acc = __builtin_amdgcn_mfma_f32_16x16x32_bf16(ah, bl, acc, 0, 0, 0);
        }
        __syncthreads();
    }
    // epilogue: s,t partials + C tile. C[row=d=w_c*16+g*4+reg][col=i=w_i*16+lm]
    float4 as4 = *(const float4*)(a_src + h * DD + w_c * 16 + g * 4);
    float4 ad4 = *(const float4*)(a_dst + h * DD + w_c * 16 + g * 4);
    float sp = acc[0] * as4.x + acc[1] * as4.y + acc[2] * as4.z + acc[3] * as4.w;
    float tp = acc[0] * ad4.x + acc[1] * ad4.y + acc[2] * ad4.z + acc[3] * ad4.w;
    sp += __shfl_xor(sp, 16); sp += __shfl_xor(sp, 32);
    tp += __shfl_xor(tp, 16); tp += __shfl_xor(tp, 32);
    if (lane < 16) { SP[w_i * 16 + lm][w_c] = sp; TP[w_i * 16 + lm][w_c] = tp; }
    #pragma unroll
    for (int reg = 0; reg < 4; ++reg) {
        int d = w_c * 16 + g * 4 + reg;
        P[d * 64 + w_i * 16 + lm] = bf16rne(acc[reg]);
    }
    __syncthreads();
    const float LOG2E = 1.4426950408889634f;
    if (tid < 64) {
        int i = i0 + tid;
        s[h * NN + i] = (SP[tid][0] + SP[tid][1] + SP[tid][2] + SP[tid][3]) * LOG2E;
        t[h * NN + i] = (TP[tid][0] + TP[tid][1] + TP[tid][2] + TP[tid][3]) * LOG2E;
    }
    ushort* tbase = WhbT + ((size_t)(h * 64 + it)) * 4096;
    if (tid < 512) {
        uint4 v = *(const uint4*)(P + tid * 8);
        *(uint4*)(tbase + tid * 8) = v;
    }
}

// ---------- Kernel 3: partial masked-softmax aggregation via 32x32x16 MFMA ----------
// grid (NN/128, HH, js); 256 thr = 4 waves; each wave owns 32 rows.
// A-frag: row=lane&31, k=(lane>>5)*8+e. C/D: col=lane&31, row=(reg&3)+8*(reg>>2)+4*(lane>>5).
__global__ __launch_bounds__(256, 6) void k_aggp(const ushort* __restrict__ WhbT,
                                                 const float* __restrict__ s,
                                                 const float* __restrict__ t,
                                                 const u64* __restrict__ bm,
                                                 float* __restrict__ pacc,
                                                 float* __restrict__ pl,
                                                 int ntiles) {
    __shared__ ushort Vt[8192];     // 2 bufs x 8KB, swizzled image
    int h = blockIdx.y;
    int i0 = blockIdx.x * 128;
    int z = blockIdx.z;
    int tid = threadIdx.x;
    int w = tid >> 6, lane = tid & 63, r = lane & 31, hi = lane >> 5;
    int irow = i0 + w * 32 + r;
    float s_i = s[(size_t)h * NN + irow];   // pre-scaled by log2e
    const float* tb_t = t + (size_t)h * NN;
    f32x16 acc0 = {}, acc1 = {};
    float lacc = 0.f;
    int jt0 = z * ntiles;
    auto stage = [&](int p, int jt) {
        const ushort* tb = WhbT + ((size_t)(h * 64 + jt)) * 4096;
        #pragma unroll
        for (int sub = 0; sub < 2; ++sub) {
            int y0 = sub * 256 + w * 64;           // wave-uniform chunk base
            int y = y0 + lane;
            int sy = y ^ ((y >> 3) & 7);           // sigma source chunk
            GLOAD_LDS16(tb + sy * 8, Vt + p * 4096 + y0 * 8);
        }
    };
    stage(0, jt0);
    int p = 0;
    for (int jj = 0; jj < ntiles; ++jj) {
        int jt = jt0 + jj, j0 = jt * 64;
        __syncthreads();                 // buf[p] DMA complete; prev reads done
        if (jj + 1 < ntiles) stage(p ^ 1, jt + 1);
        u64 bits = bm[(size_t)irow * 64 + jt];
        #pragma unroll
        for (int jq = 0; jq < 4; ++jq) {
            int kb = jq * 16 + hi * 8;             // j-offset for this lane's A k-slots
            float4 t0 = *(const float4*)(tb_t + j0 + kb);
            float4 t1 = *(const float4*)(tb_t + j0 + kb + 4);
            float ta[8] = {t0.x, t0.y, t0.z, t0.w, t1.x, t1.y, t1.z, t1.w};
            u32 msk = (u32)(bits >> kb) & 0xffu;
            float wv[8];
            #pragma unroll
            for (int e = 0; e < 8; ++e) {
                float zz = s_i + ta[e];
                zz = fmaxf(zz, 0.2f * zz);         // LeakyReLU (log2-domain)
                float ex = EXP2F(zz);
                wv[e] = ((msk >> e) & 1u) ? ex : 0.f;
                lacc += wv[e];
            }
            union { u32 u[4]; short8 v; } au;
            #pragma unroll
            for (int q = 0; q < 4; ++q) {
                __hip_bfloat162 b2 = __float22bfloat162_rn(make_float2(wv[2 * q], wv[2 * q + 1]));
                au.u[q] = *(u32*)&b2;
            }
            // B-frags: col=r -> d = dh*32+r; k slots = 8 consecutive j at kb
            u32 sw = ((u32)(jq * 32 + hi * 16)) ^ ((u32)(r & 7) << 4);
            u32 o0 = (u32)(p * 8192) + (u32)(r * 128) + sw;
            u32 o1 = o0 + 32 * 128;
            short8 b0 = *(const short8*)((const char*)Vt + o0);
            short8 b1 = *(const short8*)((const char*)Vt + o1);
            __builtin_amdgcn_s_setprio(1);
            acc0 = __builtin_amdgcn_mfma_f32_32x32x16_bf16(au.v, b0, acc0, 0, 0, 0);
            acc1 = __builtin_amdgcn_mfma_f32_32x32x16_bf16(au.v, b1, acc1, 0, 0, 0);
            __builtin_amdgcn_s_setprio(0);
        }
        p ^= 1;
    }
    // epilogue: l for row r (combine hi halves), then C-layout partial store
    lacc += __shfl_xor(lacc, 32);
    size_t pbase = ((size_t)z * HH + h) * NN;
    if (lane < 32) pl[pbase + i0 + w * 32 + lane] = lacc;
    #pragma unroll
    for (int reg = 0; reg < 16; ++reg) {
        int row = (reg & 3) + 8 * (reg >> 2) + 4 * hi;
        size_t o = (pbase + i0 + w * 32 + row) * DD + r;
        pacc[o]      = acc0[reg];
        pacc[o + 32] = acc1[reg];
    }
}

// ---------- Kernel 4: combine partials, normalize, ELU ----------
__global__ __launch_bounds__(256) void k_comb(const float* __restrict__ pacc,
                                              const float* __restrict__ pl,
                                              float* __restrict__ out, int js) {
    int gid = blockIdx.x * 256 + threadIdx.x;   // H*N*16 threads, 4 d's each
    int dgi = gid & 15;
    int hn = gid >> 4;
    int h = hn >> 12, n = hn & (NN - 1);
    f32x4 acc = {};
    float l = 0.f;
    for (int zz = 0; zz < js; ++zz) {
        const f32x4* pp = (const f32x4*)(pacc + ((size_t)zz * HH * NN + hn) * DD + dgi * 4);
        acc += *pp;
        l += pl[(size_t)zz * HH * NN + hn];
    }
    float inv = 1.f / l;
    float rr[4];
    #pragma unroll
    for (int dd = 0; dd < 4; ++dd) {
        float u = acc[dd] * inv;
        rr[dd] = u > 0.f ? u : __expf(u) - 1.f;
    }
    *(float4*)&out[(size_t)n * (HH * DD) + h * DD + dgi * 4] =
        make_float4(rr[0], rr[1], rr[2], rr[3]);
}

extern "C" void kernel_launch(void* const* d_in, const int* in_sizes, int n_in,
                              void* d_out, int out_size, void* d_ws, size_t ws_size,
                              hipStream_t stream) {
    const float* x     = (const float*)d_in[0];
    const int*   adj   = (const int*)d_in[1];
    const float* W     = (const float*)d_in[2];
    const float* a_src = (const float*)d_in[3];
    const float* a_dst = (const float*)d_in[4];
    float* out = (float*)d_out;

    char* ws = (char*)d_ws;
    const size_t MB = 1024 * 1024;
    ushort* WhbT = (ushort*)ws;                         // 4 MB, linear tiles
    u64*    bm   = (u64*)(ws + 4 * MB);                 // 2 MB
    float*  s    = (float*)(ws + 6 * MB);               // 128 KB
    float*  t    = (float*)(ws + 6 * MB + 128 * 1024);  // 128 KB
    // early region (dead after k_proj) — pacc aliases it
    ushort* xh  = (ushort*)(ws + 6 * MB + 256 * 1024);              // 4 MB
    ushort* xl  = (ushort*)(ws + 10 * MB + 256 * 1024);             // 4 MB
    ushort* WTs = (ushort*)(ws + 14 * MB + 256 * 1024);             // 1 MB
    size_t pacc_off = 6 * MB + 256 * 1024;

    size_t per  = (size_t)HH * NN * DD * 4;             // pacc bytes per split
    size_t perl = (size_t)HH * NN * 4;                  // pl bytes per split
    int js = 8;
    while (js > 1 && pacc_off + (size_t)js * (per + perl) > ws_size) js >>= 1;
    float* pacc = (float*)(ws + pacc_off);
    float* pl   = (float*)(ws + pacc_off + (size_t)js * per);
    int ntiles = (NN / 64) / js;

    k_bitpack<<<dim3(NN * NN / 256), dim3(256), 0, stream>>>(adj, bm);
    k_prepx<<<dim3(NN * FIN / 4 / 256), dim3(256), 0, stream>>>(x, xh, xl);
    k_prepw<<<dim3(HH * 8 * 64 * 8 / 256), dim3(256), 0, stream>>>(W, WTs);
    k_proj<<<dim3(NN / 64, HH), dim3(1024), 0, stream>>>(xh, xl, WTs, a_src, a_dst, WhbT, s, t);
    k_aggp<<<dim3(NN / 128, HH, js), dim3(256), 0, stream>>>(WhbT, s, t, bm, pacc, pl, ntiles);
    k_comb<<<dim3(HH * NN * 16 / 256), dim3(256), 0, stream>>>(pacc, pl, out, js);
}

// Round 7
// 91.362 us; speedup vs baseline: 1.5911x; 1.1735x over previous
//
#include <hip/hip_runtime.h>
#include <hip/hip_bf16.h>
#include <math.h>

#define NN 4096
#define FIN 512
#define HH 8
#define DD 64

typedef unsigned long long u64;
typedef unsigned int u32;
typedef float f32x4 __attribute__((ext_vector_type(4)));
typedef float f32x16 __attribute__((ext_vector_type(16)));
typedef short short8 __attribute__((ext_vector_type(8)));

#define GLOAD_LDS16(g, l)                                                              \
  __builtin_amdgcn_global_load_lds((const __attribute__((address_space(1))) u32*)(g),  \
                                   (__attribute__((address_space(3))) u32*)(l), 16, 0, 0)

#if __has_builtin(__builtin_amdgcn_exp2f)
#define EXP2F(x) __builtin_amdgcn_exp2f(x)
#else
#define EXP2F(x) exp2f(x)
#endif

__device__ inline ushort bf16rne(float f) {
    u32 u = __float_as_uint(f);
    u += 0x7FFFu + ((u >> 16) & 1u);
    return (ushort)(u >> 16);
}
__device__ inline float bf16tof(ushort h) {
    return __uint_as_float(((u32)h) << 16);
}

// ---------- Kernel 1: bit-pack adjacency: bm[i][jw] (u64, bit j%64) ----------
__global__ __launch_bounds__(256) void k_bitpack(const int* __restrict__ adj,
                                                 u64* __restrict__ bm) {
    int tid = blockIdx.x * 256 + threadIdx.x;
    int lane = threadIdx.x & 63;
    int v = adj[tid];
    u64 m = __ballot(v > 0);
    if (lane == 0) bm[tid >> 6] = m;
}

// ---------- Kernel 1b: split x -> bf16 hi/lo (row-major [i][f]) ----------
__global__ __launch_bounds__(256) void k_prepx(const float* __restrict__ x,
                                               ushort* __restrict__ xh,
                                               ushort* __restrict__ xl) {
    int tid = blockIdx.x * 256 + threadIdx.x;      // NN*FIN/4 threads
    float4 v = *(const float4*)(x + (size_t)tid * 4);
    float fa[4] = {v.x, v.y, v.z, v.w};
    ushort4 hh, ll;
    ushort* hp = (ushort*)&hh; ushort* lp = (ushort*)&ll;
    #pragma unroll
    for (int k = 0; k < 4; ++k) {
        ushort hv = bf16rne(fa[k]);
        hp[k] = hv;
        lp[k] = bf16rne(fa[k] - bf16tof(hv));
    }
    *(ushort4*)(xh + (size_t)tid * 4) = hh;
    *(ushort4*)(xl + (size_t)tid * 4) = ll;
}

// ---------- Kernel 1c: W -> WTs tiles [h*2+split][kt][d(64)][k(64)] bf16, linear ----------
__global__ __launch_bounds__(256) void k_prepw(const float* __restrict__ W,
                                               ushort* __restrict__ WTs) {
    int gid = blockIdx.x * 256 + threadIdx.x;      // 32768 threads
    int d = gid & 63, kg = (gid >> 6) & 7, kt = (gid >> 9) & 7, h = gid >> 12;
    ushort hh[8], ll[8];
    #pragma unroll
    for (int e = 0; e < 8; ++e) {
        int f = kt * 64 + kg * 8 + e;
        float wv = W[((size_t)h * FIN + f) * DD + d];
        ushort hv = bf16rne(wv);
        hh[e] = hv;
        ll[e] = bf16rne(wv - bf16tof(hv));
    }
    *(uint4*)(WTs + ((size_t)((h * 2 + 0) * 8 + kt)) * 4096 + d * 64 + kg * 8) = *(uint4*)hh;
    *(uint4*)(WTs + ((size_t)((h * 2 + 1) * 8 + kt)) * 4096 + d * 64 + kg * 8) = *(uint4*)ll;
}

// ---------- Kernel 2: MFMA projection, LDS-staged, 16 waves/block ----------
// grid (NN/64, HH), 1024 thr. Outputs WhbT linear tiles [h][it][d(64)][j(64)] bf16;
// s (f32) and tb16 (bf16) both pre-scaled by log2e.
__global__ __launch_bounds__(1024) void k_proj(const ushort* __restrict__ xh,
                                               const ushort* __restrict__ xl,
                                               const ushort* __restrict__ WTs,
                                               const float* __restrict__ a_src,
                                               const float* __restrict__ a_dst,
                                               ushort* __restrict__ WhbT,
                                               float* __restrict__ s,
                                               ushort* __restrict__ tb16) {
    __shared__ ushort P[16384];        // 4 bufs (Ah,Al,Bh,Bl) x 8KB, swizzled image
    __shared__ float SP[64][5], TP[64][5];
    int h = blockIdx.y, it = blockIdx.x;
    int i0 = it * 64;
    int tid = threadIdx.x;
    int w = tid >> 6, lane = tid & 63, lm = lane & 15, g = lane >> 4;
    int w_c = w & 3, w_i = w >> 2;
    f32x4 acc = {};
    int da = w_c * 16 + lm, ib = w_i * 16 + lm;
    for (int kt = 0; kt < 8; ++kt) {
        #pragma unroll
        for (int sub = 0; sub < 2; ++sub) {
            int buf = sub * 2 + (w >> 3);          // wave-uniform
            int y0 = (w & 7) * 64;                 // wave-uniform chunk base
            int y = y0 + lane;
            int r = y >> 3;
            int cc = (y & 7) ^ (r & 7);            // sigma: inverse-swizzle source
            const ushort* src;
            if (buf == 0)      src = WTs + ((size_t)((h * 2 + 0) * 8 + kt)) * 4096 + r * 64 + cc * 8;
            else if (buf == 1) src = WTs + ((size_t)((h * 2 + 1) * 8 + kt)) * 4096 + r * 64 + cc * 8;
            else if (buf == 2) src = xh + (size_t)(i0 + r) * FIN + kt * 64 + cc * 8;
            else               src = xl + (size_t)(i0 + r) * FIN + kt * 64 + cc * 8;
            GLOAD_LDS16(src, P + buf * 4096 + y0 * 8);
        }
        __syncthreads();
        #pragma unroll
        for (int ks = 0; ks < 2; ++ks) {
            u32 offA = ((u32)(da * 128 + ks * 64 + g * 16)) ^ ((u32)(da & 7) << 4);
            u32 offB = ((u32)(ib * 128 + ks * 64 + g * 16)) ^ ((u32)(ib & 7) << 4);
            short8 ah = *(const short8*)((const char*)P + offA);
            short8 al = *(const short8*)((const char*)P + 8192 + offA);
            short8 bh = *(const short8*)((const char*)P + 16384 + offB);
            short8 bl = *(const short8*)((const char*)P + 24576 + offB);
            acc = __builtin_amdgcn_mfma_f32_16x16x32_bf16(ah, bh, acc, 0, 0, 0);
            acc = __builtin_amdgcn_mfma_f32_16x16x32_bf16(al, bh, acc, 0, 0, 0);
            acc = __builtin_amdgcn_mfma_f32_16x16x32_bf16(ah, bl, acc, 0, 0, 0);
        }
        __syncthreads();
    }
    // epilogue: s,t partials + C tile. C[row=d=w_c*16+g*4+reg][col=i=w_i*16+lm]
    float4 as4 = *(const float4*)(a_src + h * DD + w_c * 16 + g * 4);
    float4 ad4 = *(const float4*)(a_dst + h * DD + w_c * 16 + g * 4);
    float sp = acc[0] * as4.x + acc[1] * as4.y + acc[2] * as4.z + acc[3] * as4.w;
    float tp = acc[0] * ad4.x + acc[1] * ad4.y + acc[2] * ad4.z + acc[3] * ad4.w;
    sp += __shfl_xor(sp, 16); sp += __shfl_xor(sp, 32);
    tp += __shfl_xor(tp, 16); tp += __shfl_xor(tp, 32);
    if (lane < 16) { SP[w_i * 16 + lm][w_c] = sp; TP[w_i * 16 + lm][w_c] = tp; }
    #pragma unroll
    for (int reg = 0; reg < 4; ++reg) {
        int d = w_c * 16 + g * 4 + reg;
        P[d * 64 + w_i * 16 + lm] = bf16rne(acc[reg]);
    }
    __syncthreads();
    const float LOG2E = 1.4426950408889634f;
    if (tid < 64) {
        int i = i0 + tid;
        s[h * NN + i] = (SP[tid][0] + SP[tid][1] + SP[tid][2] + SP[tid][3]) * LOG2E;
        tb16[h * NN + i] =
            bf16rne((TP[tid][0] + TP[tid][1] + TP[tid][2] + TP[tid][3]) * LOG2E);
    }
    ushort* tbase = WhbT + ((size_t)(h * 64 + it)) * 4096;
    if (tid < 512) {
        uint4 v = *(const uint4*)(P + tid * 8);
        *(uint4*)(tbase + tid * 8) = v;
    }
}

// ---------- Kernel 3: FUSED masked-softmax aggregation + ELU + out write ----------
// grid (NN/64, HH), 512 thr = 4 j-groups x 2 waves x 32 rows; full j in-block.
// Group g owns j-quarter [g*1024, (g+1)*1024), private dbuf Vt; in-LDS combine.
__global__ __launch_bounds__(512, 4) void k_agg(const ushort* __restrict__ WhbT,
                                                const float* __restrict__ s,
                                                const ushort* __restrict__ tb16,
                                                const u64* __restrict__ bm,
                                                float* __restrict__ out) {
    __shared__ __attribute__((aligned(16))) char SM[73728];
    ushort* Vt  = (ushort*)SM;                 // 64KB: group g at g*16384, buf p at +p*8192
    ushort* tls = (ushort*)(SM + 65536);       // 8KB bf16 t (log2-scaled), whole j-range
    float*  PL  = (float*)(SM + 65536);        // reused for l-partials after loop (t dead)
    int h = blockIdx.y;
    int i0 = blockIdx.x * 64;
    int tid = threadIdx.x;
    int w = tid >> 6, lane = tid & 63, r = lane & 31, hi = lane >> 5;
    int g = w >> 1, wr = w & 1;
    int irow = i0 + wr * 32 + r;
    float s_i = s[(size_t)h * NN + irow];      // pre-scaled by log2e
    // stage t (4096 bf16 = 8KB) once
    *(uint4*)(tls + tid * 8) = *(const uint4*)(tb16 + (size_t)h * NN + tid * 8);
    f32x16 acc0 = {}, acc1 = {};
    float lacc = 0.f;
    int jtbase = g * 16;
    auto stage = [&](int p, int k) {
        const ushort* tb = WhbT + ((size_t)(h * 64 + jtbase + k)) * 4096;
        #pragma unroll
        for (int sub = 0; sub < 4; ++sub) {
            int y0 = wr * 256 + sub * 64;          // wave-uniform chunk base
            int y = y0 + lane;
            int sy = y ^ ((y >> 3) & 7);           // sigma source chunk
            GLOAD_LDS16(tb + sy * 8, (char*)Vt + g * 16384 + p * 8192 + y0 * 16);
        }
    };
    stage(0, 0);
    u64 bits = bm[(size_t)irow * 64 + jtbase];
    for (int k = 0; k < 16; ++k) {
        __syncthreads();                 // vmcnt drained: buf[k&1] + tls ready
        if (k + 1 < 16) stage((k + 1) ^ (k & 1) ? (k + 1) & 1 : (k + 1) & 1, k + 1);
        u64 bnext = (k + 1 < 16) ? bm[(size_t)irow * 64 + jtbase + k + 1] : 0;
        int jt = jtbase + k;
        #pragma unroll
        for (int jq = 0; jq < 4; ++jq) {
            int kb = jq * 16 + hi * 8;
            short8 tv = *(const short8*)((const char*)tls + jt * 128 + jq * 32 + hi * 16);
            u32 msk = (u32)(bits >> kb) & 0xffu;
            float wv[8];
            #pragma unroll
            for (int e = 0; e < 8; ++e) {
                float zz = s_i + bf16tof((ushort)tv[e]);
                zz = fmaxf(zz, 0.2f * zz);         // LeakyReLU (log2-domain)
                float ex = EXP2F(zz);
                wv[e] = ((msk >> e) & 1u) ? ex : 0.f;
                lacc += wv[e];
            }
            union { u32 u[4]; short8 v; } au;
            #pragma unroll
            for (int q = 0; q < 4; ++q) {
                __hip_bfloat162 b2 = __float22bfloat162_rn(make_float2(wv[2 * q], wv[2 * q + 1]));
                au.u[q] = *(u32*)&b2;
            }
            u32 o0 = (u32)(g * 16384 + (k & 1) * 8192) + (u32)(r * 128) +
                     (((u32)(jq * 32 + hi * 16)) ^ ((u32)(r & 7) << 4));
            short8 b0 = *(const short8*)((const char*)Vt + o0);
            short8 b1 = *(const short8*)((const char*)Vt + o0 + 4096);
            __builtin_amdgcn_s_setprio(1);
            acc0 = __builtin_amdgcn_mfma_f32_32x32x16_bf16(au.v, b0, acc0, 0, 0, 0);
            acc1 = __builtin_amdgcn_mfma_f32_32x32x16_bf16(au.v, b1, acc1, 0, 0, 0);
            __builtin_amdgcn_s_setprio(0);
        }
        bits = bnext;
    }
    // ---- in-block combine ----
    lacc += __shfl_xor(lacc, 32);
    __syncthreads();                     // all waves done reading Vt & tls
    float* PT = (float*)(SM + g * 16384);    // [64 rows][64 d] per group
    #pragma unroll
    for (int reg = 0; reg < 16; ++reg) {
        int rowl = (reg & 3) + 8 * (reg >> 2) + 4 * hi;
        PT[(wr * 32 + rowl) * 64 + r]      = acc0[reg];
        PT[(wr * 32 + rowl) * 64 + 32 + r] = acc1[reg];
    }
    if (lane < 32) PL[g * 64 + wr * 32 + lane] = lacc;
    __syncthreads();
    // epilogue: tid -> row (0..63), d0 = 8-float group
    int row = tid >> 3, d0 = (tid & 7) * 8;
    f32x4 a0 = {}, a1 = {};
    float l = 0.f;
    #pragma unroll
    for (int gg = 0; gg < 4; ++gg) {
        const float* P = (const float*)(SM + gg * 16384) + row * 64 + d0;
        a0 += *(const f32x4*)P;
        a1 += *(const f32x4*)(P + 4);
        l += PL[gg * 64 + row];
    }
    float inv = 1.f / l;
    float o[8];
    #pragma unroll
    for (int dd = 0; dd < 4; ++dd) {
        float u0 = a0[dd] * inv;
        float u1 = a1[dd] * inv;
        o[dd]     = u0 > 0.f ? u0 : __expf(u0) - 1.f;
        o[dd + 4] = u1 > 0.f ? u1 : __expf(u1) - 1.f;
    }
    float* ob = out + (size_t)(i0 + row) * (HH * DD) + h * DD + d0;
    *(float4*)ob       = make_float4(o[0], o[1], o[2], o[3]);
    *(float4*)(ob + 4) = make_float4(o[4], o[5], o[6], o[7]);
}

extern "C" void kernel_launch(void* const* d_in, const int* in_sizes, int n_in,
                              void* d_out, int out_size, void* d_ws, size_t ws_size,
                              hipStream_t stream) {
    const float* x     = (const float*)d_in[0];
    const int*   adj   = (const int*)d_in[1];
    const float* W     = (const float*)d_in[2];
    const float* a_src = (const float*)d_in[3];
    const float* a_dst = (const float*)d_in[4];
    float* out = (float*)d_out;

    char* ws = (char*)d_ws;
    const size_t MB = 1024 * 1024;
    ushort* WhbT = (ushort*)ws;                          // 4 MB, linear tiles
    u64*    bm   = (u64*)(ws + 4 * MB);                  // 2 MB
    float*  s    = (float*)(ws + 6 * MB);                // 128 KB
    ushort* tb16 = (ushort*)(ws + 6 * MB + 128 * 1024);  // 64 KB
    ushort* xh   = (ushort*)(ws + 7 * MB);               // 4 MB
    ushort* xl   = (ushort*)(ws + 11 * MB);              // 4 MB
    ushort* WTs  = (ushort*)(ws + 15 * MB);              // 1 MB

    k_bitpack<<<dim3(NN * NN / 256), dim3(256), 0, stream>>>(adj, bm);
    k_prepx<<<dim3(NN * FIN / 4 / 256), dim3(256), 0, stream>>>(x, xh, xl);
    k_prepw<<<dim3(HH * 8 * 64 * 8 / 256), dim3(256), 0, stream>>>(W, WTs);
    k_proj<<<dim3(NN / 64, HH), dim3(1024), 0, stream>>>(xh, xl, WTs, a_src, a_dst, WhbT, s, tb16);
    k_agg<<<dim3(NN / 64, HH), dim3(512), 0, stream>>>(WhbT, s, tb16, bm, out);
}